// Round 13
// baseline (157.313 us; speedup 1.0000x reference)
//
#include <hip/hip_runtime.h>
#include <math.h>

typedef _Float16 h2 __attribute__((ext_vector_type(2)));
typedef _Float16 h4 __attribute__((ext_vector_type(4)));
typedef _Float16 h8 __attribute__((ext_vector_type(8)));
typedef float f8 __attribute__((ext_vector_type(8)));

#define NEG_SLOPE 0.2f
#define LN_EPS 1e-5f
#define RESCALE_THR 8.0f
#define SLOT 64

#if __has_builtin(__builtin_amdgcn_fdot2)
#define FDOT2(a, b, c) __builtin_amdgcn_fdot2((a), (b), (c), false)
#else
static __device__ __forceinline__ float FDOT2(h2 a, h2 b, float c) {
    return c + (float)a[0] * (float)b[0] + (float)a[1] * (float)b[1];
}
#endif

// sum over the 8-lane head group (lane bits 0..2) with pure-VALU DPP ops
static __device__ __forceinline__ float red8_dpp(float p) {
    p += __int_as_float(__builtin_amdgcn_mov_dpp(__float_as_int(p), 0xB1, 0xF, 0xF, true));  // quad_perm xor1
    p += __int_as_float(__builtin_amdgcn_mov_dpp(__float_as_int(p), 0x4E, 0xF, 0xF, true));  // quad_perm xor2
    p += __int_as_float(__builtin_amdgcn_mov_dpp(__float_as_int(p), 0x141, 0xF, 0xF, true)); // row_half_mirror
    return p;
}

static __device__ __forceinline__ _Float16 f16_bits(unsigned short u) {
    union { unsigned short u; _Float16 h; } c; c.u = u; return c.h;
}
static __device__ __forceinline__ unsigned short bits_f16(_Float16 h) {
    union { unsigned short u; _Float16 h; } c; c.h = h; return c.u;
}

// ---------------- K0: zero cursor ----------------
__global__ void init_kernel(int* __restrict__ cursor, int n) {
    int i = blockIdx.x * 256 + threadIdx.x;
    if (i < n) cursor[i] = 0;
}

// ---------------- K1: fill (blocks < EB) + transform (blocks >= EB), concurrent ----------------
__global__ __launch_bounds__(256) void prep_kernel(
    const int* __restrict__ ei, const float* __restrict__ ea,
    int* __restrict__ cursor, unsigned int* __restrict__ rec, float* __restrict__ partials,
    const float* __restrict__ x, const float* __restrict__ Wl, const float* __restrict__ bl,
    const float* __restrict__ Wr, const float* __restrict__ br,
    _Float16* __restrict__ xlh, _Float16* __restrict__ xrh,
    int N, int E, int EB) {
    int b = blockIdx.x, t = threadIdx.x;
    if (b < EB) {
        // ---- fill: bucket edges into per-dst slots (packed u32) + ea partial ----
        int i = b * 256 + t;
        float s = 0.f;
        if (i < E) {
            int src = ei[i];
            int dst = ei[E + i];
            float a = ea[i];
            s = a;
            int pos = atomicAdd(&cursor[dst], 1);
            if (pos < SLOT) {
                unsigned int pk = ((unsigned int)bits_f16((_Float16)a) << 16) | (unsigned int)src;
                rec[(size_t)dst * SLOT + pos] = pk;
            }
        }
        __shared__ float red[4];
#pragma unroll
        for (int o = 32; o >= 1; o >>= 1) s += __shfl_xor(s, o);
        if ((t & 63) == 0) red[t >> 6] = s;
        __syncthreads();
        if (t == 0) partials[b] = red[0] + red[1] + red[2] + red[3];
    } else {
        // ---- transform: 8 nodes per block -> fp16, 2-deep W-load pipeline ----
        __shared__ float xs[8][64];
        int nb = (b - EB) * 8;
        int rows = N - nb; if (rows > 8) rows = 8;
        if (rows <= 0) return;
        if (t < rows * 16) ((float4*)xs)[t] = ((const float4*)(x + (size_t)nb * 64))[t];
        __syncthreads();
        float blv = bl[t], brv = br[t];
        float accl[8], accr[8];
#pragma unroll
        for (int i = 0; i < 8; ++i) { accl[i] = blv; accr[i] = brv; }

        float Al0, Al1, Al2, Al3, Ar0, Ar1, Ar2, Ar3;
        float Bl0, Bl1, Bl2, Bl3, Br0, Br1, Br2, Br3;
#define WLOAD(P, K)                                                     \
        P##l0 = Wl[(K + 0) * 256 + t]; P##l1 = Wl[(K + 1) * 256 + t];   \
        P##l2 = Wl[(K + 2) * 256 + t]; P##l3 = Wl[(K + 3) * 256 + t];   \
        P##r0 = Wr[(K + 0) * 256 + t]; P##r1 = Wr[(K + 1) * 256 + t];   \
        P##r2 = Wr[(K + 2) * 256 + t]; P##r3 = Wr[(K + 3) * 256 + t];
#define WFMA(P, K)                                                      \
        _Pragma("unroll")                                               \
        for (int i = 0; i < 8; ++i) {                                   \
            float4 xv = *(const float4*)&xs[i][K];                      \
            accl[i] += xv.x * P##l0 + xv.y * P##l1 + xv.z * P##l2 + xv.w * P##l3; \
            accr[i] += xv.x * P##r0 + xv.y * P##r1 + xv.z * P##r2 + xv.w * P##r3; \
        }
        WLOAD(A, 0)
        WLOAD(B, 4)
        WFMA(A, 0)  WLOAD(A, 8)
        WFMA(B, 4)  WLOAD(B, 12)
        WFMA(A, 8)  WLOAD(A, 16)
        WFMA(B, 12) WLOAD(B, 20)
        WFMA(A, 16) WLOAD(A, 24)
        WFMA(B, 20) WLOAD(B, 28)
        WFMA(A, 24) WLOAD(A, 32)
        WFMA(B, 28) WLOAD(B, 36)
        WFMA(A, 32) WLOAD(A, 40)
        WFMA(B, 36) WLOAD(B, 44)
        WFMA(A, 40) WLOAD(A, 48)
        WFMA(B, 44) WLOAD(B, 52)
        WFMA(A, 48) WLOAD(A, 56)
        WFMA(B, 52) WLOAD(B, 60)
        WFMA(A, 56)
        WFMA(B, 60)
#undef WLOAD
#undef WFMA
        for (int i = 0; i < rows; ++i) {
            xlh[(size_t)(nb + i) * 256 + t] = (_Float16)accl[i];
            xrh[(size_t)(nb + i) * 256 + t] = (_Float16)accr[i];
        }
    }
}

// ---------------- K2: reduce ea partials -> easum (premultiplied by 1/E) ----------------
__global__ __launch_bounds__(256) void easum_kernel(const float* __restrict__ partials,
                                                    float* __restrict__ easum, int eb, float inv_e) {
    float s = 0.f;
    for (int i = threadIdx.x; i < eb; i += 256) s += partials[i];
#pragma unroll
    for (int o = 32; o >= 1; o >>= 1) s += __shfl_xor(s, o);
    __shared__ float red[4];
    if ((threadIdx.x & 63) == 0) red[threadIdx.x >> 6] = s;
    __syncthreads();
    if (threadIdx.x == 0) easum[0] = (red[0] + red[1] + red[2] + red[3]) * inv_e;
}

// ---------------- K3: per-node GATv2, lane-resident records (readlane fetch) ----------------
// Record fetch via v_readlane (EXEC-independent, SGPR result) — uniform indices,
// no ds_bpermute in the serial chain; loop bounds are wave-uniform (cnt).
__global__ __launch_bounds__(256) void gat_kernel(
    const _Float16* __restrict__ xlh, const _Float16* __restrict__ xrh,
    const int* __restrict__ cursor, const unsigned int* __restrict__ rec,
    const float* __restrict__ att, const float* __restrict__ We, const float* __restrict__ bias_conv,
    const float* __restrict__ easum, _Float16* __restrict__ hg, int n) {
    int wid = (blockIdx.x * blockDim.x + threadIdx.x) >> 6;
    if (wid >= n) return;
    int lane = threadIdx.x & 63;
    int half = lane >> 5, s = lane & 31;      // lane covers dims 8s..8s+7

    // one coalesced load: lane l holds record l of this node (garbage for l>=cnt, never used)
    int pkv = (int)rec[(size_t)wid * SLOT + lane];
    int cnt = cursor[wid]; if (cnt > SLOT) cnt = SLOT;   // wave-uniform

    h8 xrv = ((const h8*)xrh)[(size_t)wid * 32 + s];
    h2 xr2[4], we2[4], c02 = {(_Float16)NEG_SLOPE, (_Float16)NEG_SLOPE};
    float atf[8];
    const float* attp = att + 8 * s;
    const float* wep = We + 8 * s;
#pragma unroll
    for (int j = 0; j < 4; ++j) {
        xr2[j] = (h2){xrv[2 * j], xrv[2 * j + 1]};
        we2[j] = (h2){(_Float16)wep[2 * j], (_Float16)wep[2 * j + 1]};
        atf[2 * j] = attp[2 * j]; atf[2 * j + 1] = attp[2 * j + 1];
    }
    const h8* xl8 = (const h8*)xlh;

    auto edge_p = [&](h8 v, _Float16 ah) -> float {
        h2 a2 = {ah, ah};
        float p = 0.f;
#pragma unroll
        for (int j = 0; j < 4; ++j) {
            h2 vj = (h2){v[2 * j], v[2 * j + 1]};
            h2 m = a2 * we2[j] + (vj + xr2[j]);
            h2 l = __builtin_elementwise_max(m, m * c02);   // leaky relu
            p = fmaf((float)l[0], atf[2 * j], p);
            p = fmaf((float)l[1], atf[2 * j + 1], p);
        }
        return red8_dpp(p);
    };

    float M = -1e30f, S = 0.f;
    f8 accv = (f8)0.f;                        // ext_vector: guaranteed registers

#define ACC_FMA(V, W)                                        \
    _Pragma("unroll")                                        \
    for (int j = 0; j < 8; ++j) accv[j] = fmaf((float)(V)[j], (W), accv[j]);

#define ONLINE(P, V) {                                       \
        float newM = fmaxf(M, (P));                          \
        float sc = __expf(M - newM), w = __expf((P) - newM); \
        S = S * sc + w;                                      \
        accv *= sc;                                          \
        ACC_FMA(V, w);                                       \
        M = newM; }

// record (R)+2*(D)+half via EXEC-independent readlane pair + per-lane select
#define LOADE(D, R)                                                         \
    int lo##D = __builtin_amdgcn_readlane(pkv, (R) + 2 * (D));              \
    int hi##D = __builtin_amdgcn_readlane(pkv, (R) + 2 * (D) + 1);          \
    int pk##D = half ? hi##D : lo##D;                                       \
    h8 v##D = xl8[(size_t)(unsigned)(pk##D & 0xFFFF) * 32 + s];
#define PCOMP(D) float p##D = edge_p(v##D, f16_bits((unsigned short)((unsigned)pk##D >> 16)));

    // prologue: half 0 = self loop (always), half 1 = record 0 (if cnt>=1)
    {
        int pk0 = __builtin_amdgcn_readlane(pkv, 0);
        int src = wid;
        _Float16 ah = (_Float16)easum[0];
        if (half == 1 && cnt >= 1) {
            src = pk0 & 0xFFFF;
            ah = f16_bits((unsigned short)((unsigned)pk0 >> 16));
        }
        h8 v = xl8[(size_t)src * 32 + s];
        float p = edge_p(v, ah);
        if (half == 0 || cnt >= 1) {
            M = p; S = 1.f;
#pragma unroll
            for (int j = 0; j < 8; ++j) accv[j] = (float)v[j];
        }
    }
    // remaining records: 1..cnt-1, consumed in wave-uniform blocks
    int r = 1;
    for (; r + 15 < cnt; r += 16) {
        LOADE(0, r) LOADE(1, r) LOADE(2, r) LOADE(3, r)
        LOADE(4, r) LOADE(5, r) LOADE(6, r) LOADE(7, r)
        PCOMP(0) PCOMP(1) PCOMP(2) PCOMP(3)
        PCOMP(4) PCOMP(5) PCOMP(6) PCOMP(7)
        float pm = fmaxf(fmaxf(fmaxf(p0, p1), fmaxf(p2, p3)),
                         fmaxf(fmaxf(p4, p5), fmaxf(p6, p7)));
        if (__all(pm <= M + RESCALE_THR)) {   // defer-max fast path
            float w0 = __expf(p0 - M), w1 = __expf(p1 - M);
            float w2 = __expf(p2 - M), w3 = __expf(p3 - M);
            float w4 = __expf(p4 - M), w5 = __expf(p5 - M);
            float w6 = __expf(p6 - M), w7 = __expf(p7 - M);
            S += ((w0 + w1) + (w2 + w3)) + ((w4 + w5) + (w6 + w7));
            ACC_FMA(v0, w0); ACC_FMA(v1, w1); ACC_FMA(v2, w2); ACC_FMA(v3, w3);
            ACC_FMA(v4, w4); ACC_FMA(v5, w5); ACC_FMA(v6, w6); ACC_FMA(v7, w7);
        } else {
            ONLINE(p0, v0); ONLINE(p1, v1); ONLINE(p2, v2); ONLINE(p3, v3);
            ONLINE(p4, v4); ONLINE(p5, v5); ONLINE(p6, v6); ONLINE(p7, v7);
        }
    }
    for (; r + 7 < cnt; r += 8) {
        LOADE(0, r) LOADE(1, r) LOADE(2, r) LOADE(3, r)
        PCOMP(0) PCOMP(1) PCOMP(2) PCOMP(3)
        float pm = fmaxf(fmaxf(p0, p1), fmaxf(p2, p3));
        if (__all(pm <= M + RESCALE_THR)) {
            float w0 = __expf(p0 - M), w1 = __expf(p1 - M);
            float w2 = __expf(p2 - M), w3 = __expf(p3 - M);
            S += (w0 + w1) + (w2 + w3);
            ACC_FMA(v0, w0); ACC_FMA(v1, w1); ACC_FMA(v2, w2); ACC_FMA(v3, w3);
        } else {
            ONLINE(p0, v0); ONLINE(p1, v1); ONLINE(p2, v2); ONLINE(p3, v3);
        }
    }
    for (; r + 1 < cnt; r += 2) {
        int lo = __builtin_amdgcn_readlane(pkv, r);
        int hi = __builtin_amdgcn_readlane(pkv, r + 1);
        int pk0 = half ? hi : lo;
        h8 v0 = xl8[(size_t)(unsigned)(pk0 & 0xFFFF) * 32 + s];
        PCOMP(0)
        ONLINE(p0, v0);
    }
    if (r < cnt) {   // single leftover record: readlane is EXEC-independent
        int pk0 = __builtin_amdgcn_readlane(pkv, r);
        h8 v0 = xl8[(size_t)(unsigned)(pk0 & 0xFFFF) * 32 + s];
        float p0 = edge_p(v0, f16_bits((unsigned short)((unsigned)pk0 >> 16)));
        if (half == 0) ONLINE(p0, v0);
    }

    // merge the two half-wave softmax states
    float Mo = __shfl_xor(M, 32);
    float newM = fmaxf(M, Mo);
    float sc = __expf(M - newM);
    S *= sc;
    S += __shfl_xor(S, 32);
    accv *= sc;
#pragma unroll
    for (int j = 0; j < 8; ++j) accv[j] += __shfl_xor(accv[j], 32);
    float inv = 1.f / (S + 1e-16f);

    float4 bc = ((const float4*)bias_conv)[2 * s + half];
    int jb = 4 * half;
    h4 ov = {(_Float16)(accv[jb + 0] * inv + bc.x), (_Float16)(accv[jb + 1] * inv + bc.y),
             (_Float16)(accv[jb + 2] * inv + bc.z), (_Float16)(accv[jb + 3] * inv + bc.w)};
    ((h4*)hg)[(size_t)wid * 64 + 2 * s + half] = ov;
#undef ACC_FMA
#undef ONLINE
#undef LOADE
#undef PCOMP
}

// ---------------- K4: proj(256->64) + residual + ELU + LN (64 nodes, 512 thr) ----------------
__global__ __launch_bounds__(512) void proj_ln_kernel(
    const _Float16* __restrict__ hg, const float* __restrict__ Wp, const float* __restrict__ bp,
    const float* __restrict__ x, const float* __restrict__ gamma, const float* __restrict__ beta,
    float* __restrict__ out, int n) {
    __shared__ _Float16 wp_t[64 * 256];   // transposed [c][k], XOR-swizzled; 32 KB
    __shared__ _Float16 hs[64][264];      // [node][k], +8 pad; 33.8 KB
    int t = threadIdx.x;
    int nb = blockIdx.x * 64;
    for (int idx = t; idx < 4096; idx += 512) {
        float4 wv = ((const float4*)Wp)[idx];
        int k = idx >> 4, c0s = (idx & 15) * 4;
#pragma unroll
        for (int m = 0; m < 4; ++m) {
            int c = c0s + m;
            int off = c * 256 + ((((k >> 3) ^ ((c >> 2) & 7)) << 3) | (k & 7));
            wp_t[off] = (_Float16)((&wv.x)[m]);
        }
    }
    for (int idx = t; idx < 2048; idx += 512) {
        int row = idx >> 5, c8 = idx & 31;
        h8 hv = (h8)(_Float16)0.f;
        if (nb + row < n) hv = ((const h8*)hg)[(size_t)(nb + row) * 32 + c8];
        *(h8*)&hs[row][c8 * 8] = hv;
    }
    __syncthreads();

    int ng = t >> 4, cg = t & 15;     // 32 node-pairs x 16 col-groups
    int n0 = ng * 2, c0 = cg * 4;
    float acc[2][4];
#pragma unroll
    for (int a = 0; a < 2; ++a)
#pragma unroll
        for (int c = 0; c < 4; ++c) acc[a][c] = 0.f;

    for (int k = 0; k < 256; k += 8) {
        h8 hr[2], wr_[4];
#pragma unroll
        for (int a = 0; a < 2; ++a) hr[a] = *(const h8*)&hs[n0 + a][k];
#pragma unroll
        for (int j = 0; j < 4; ++j) {
            int c = c0 + j;
            int off = c * 256 + (((k >> 3) ^ ((c >> 2) & 7)) << 3);
            wr_[j] = *(const h8*)&wp_t[off];
        }
#pragma unroll
        for (int a = 0; a < 2; ++a) {
            const h2* hp = (const h2*)&hr[a];
#pragma unroll
            for (int j = 0; j < 4; ++j) {
                const h2* wp2 = (const h2*)&wr_[j];
                acc[a][j] = FDOT2(hp[0], wp2[0], acc[a][j]);
                acc[a][j] = FDOT2(hp[1], wp2[1], acc[a][j]);
                acc[a][j] = FDOT2(hp[2], wp2[2], acc[a][j]);
                acc[a][j] = FDOT2(hp[3], wp2[3], acc[a][j]);
            }
        }
    }

    float4 bpv = ((const float4*)bp)[cg];
    float4 gv  = ((const float4*)gamma)[cg];
    float4 bv  = ((const float4*)beta)[cg];
#pragma unroll
    for (int a = 0; a < 2; ++a) {
        int node = nb + n0 + a;
        float4 xv = make_float4(0.f, 0.f, 0.f, 0.f);
        if (node < n) xv = ((const float4*)x)[(size_t)node * 16 + cg];
        float h[4];
        h[0] = acc[a][0] + bpv.x + xv.x; h[1] = acc[a][1] + bpv.y + xv.y;
        h[2] = acc[a][2] + bpv.z + xv.z; h[3] = acc[a][3] + bpv.w + xv.w;
#pragma unroll
        for (int c = 0; c < 4; ++c) h[c] = h[c] > 0.f ? h[c] : expm1f(h[c]);
        float sum = h[0] + h[1] + h[2] + h[3];
#pragma unroll
        for (int o = 8; o >= 1; o >>= 1) sum += __shfl_xor(sum, o);
        float mu = sum * (1.f / 64.f);
        float d[4]; float s2 = 0.f;
#pragma unroll
        for (int c = 0; c < 4; ++c) { d[c] = h[c] - mu; s2 += d[c] * d[c]; }
#pragma unroll
        for (int o = 8; o >= 1; o >>= 1) s2 += __shfl_xor(s2, o);
        float r = rsqrtf(s2 * (1.f / 64.f) + LN_EPS);
        float4 ov;
        ov.x = d[0] * r * gv.x + bv.x; ov.y = d[1] * r * gv.y + bv.y;
        ov.z = d[2] * r * gv.z + bv.z; ov.w = d[3] * r * gv.w + bv.w;
        if (node < n) ((float4*)out)[(size_t)node * 16 + cg] = ov;
    }
}

// ---------------- launcher ----------------
extern "C" void kernel_launch(void* const* d_in, const int* in_sizes, int n_in,
                              void* d_out, int out_size, void* d_ws, size_t ws_size,
                              hipStream_t stream) {
    const float* x         = (const float*)d_in[0];
    const int*   ei        = (const int*)d_in[1];
    const float* ea        = (const float*)d_in[2];
    const float* Wl        = (const float*)d_in[3];
    const float* bl        = (const float*)d_in[4];
    const float* Wr        = (const float*)d_in[5];
    const float* br        = (const float*)d_in[6];
    const float* We        = (const float*)d_in[7];
    const float* att       = (const float*)d_in[8];
    const float* bias_conv = (const float*)d_in[9];
    const float* Wp        = (const float*)d_in[10];
    const float* bp        = (const float*)d_in[11];
    const float* gamma     = (const float*)d_in[12];
    const float* beta      = (const float*)d_in[13];
    float* out = (float*)d_out;

    int N = in_sizes[0] / 64;
    int E = in_sizes[2];
    int EB = (E + 255) / 256;          // fill blocks
    int TB = (N + 7) / 8;              // transform blocks

    char* w = (char*)d_ws;
    auto alloc = [&](size_t bytes) {
        char* p = w;
        w += (bytes + 255) & ~(size_t)255;
        return p;
    };
    _Float16*     xlh     = (_Float16*)    alloc((size_t)N * 256 * 2);
    _Float16*     xrh     = (_Float16*)    alloc((size_t)N * 256 * 2);
    _Float16*     hgh     = (_Float16*)    alloc((size_t)N * 256 * 2);
    unsigned int* rec     = (unsigned int*)alloc((size_t)N * SLOT * 4);
    int*          cursor  = (int*)         alloc((size_t)N * 4);
    float*        partials= (float*)       alloc((size_t)EB * 4);
    float*        easum   = (float*)       alloc(4);

    init_kernel<<<(N + 255) / 256, 256, 0, stream>>>(cursor, N);
    prep_kernel<<<EB + TB, 256, 0, stream>>>(ei, ea, cursor, rec, partials,
                                             x, Wl, bl, Wr, br, xlh, xrh, N, E, EB);
    easum_kernel<<<1, 256, 0, stream>>>(partials, easum, EB, 1.f / (float)E);
    gat_kernel<<<(N + 3) / 4, 256, 0, stream>>>(xlh, xrh, cursor, rec, att, We,
                                                bias_conv, easum, hgh, N);
    proj_ln_kernel<<<(N + 63) / 64, 512, 0, stream>>>(hgh, Wp, bp, x, gamma, beta, out, N);
}

// Round 14
// 96.014 us; speedup vs baseline: 1.6384x; 1.6384x over previous
//
#include <hip/hip_runtime.h>
#include <math.h>

typedef _Float16 h2 __attribute__((ext_vector_type(2)));
typedef _Float16 h4 __attribute__((ext_vector_type(4)));
typedef _Float16 h8 __attribute__((ext_vector_type(8)));
typedef float f8 __attribute__((ext_vector_type(8)));

#define NEG_SLOPE 0.2f
#define LN_EPS 1e-5f
#define RESCALE_THR 8.0f
#define SLOT 64

#if __has_builtin(__builtin_amdgcn_fdot2)
#define FDOT2(a, b, c) __builtin_amdgcn_fdot2((a), (b), (c), false)
#else
static __device__ __forceinline__ float FDOT2(h2 a, h2 b, float c) {
    return c + (float)a[0] * (float)b[0] + (float)a[1] * (float)b[1];
}
#endif

// sum over the 8-lane head group (lane bits 0..2) with pure-VALU DPP ops
static __device__ __forceinline__ float red8_dpp(float p) {
    p += __int_as_float(__builtin_amdgcn_mov_dpp(__float_as_int(p), 0xB1, 0xF, 0xF, true));  // quad_perm xor1
    p += __int_as_float(__builtin_amdgcn_mov_dpp(__float_as_int(p), 0x4E, 0xF, 0xF, true));  // quad_perm xor2
    p += __int_as_float(__builtin_amdgcn_mov_dpp(__float_as_int(p), 0x141, 0xF, 0xF, true)); // row_half_mirror
    return p;
}

static __device__ __forceinline__ _Float16 f16_bits(unsigned short u) {
    union { unsigned short u; _Float16 h; } c; c.u = u; return c.h;
}
static __device__ __forceinline__ unsigned short bits_f16(_Float16 h) {
    union { unsigned short u; _Float16 h; } c; c.h = h; return c.u;
}

// ---------------- K0: zero cursor + convert Wl/Wr to fp16 k-pair-packed ----------------
// wlh[kk*256+t] = (Wl[2kk][t], Wl[2kk+1][t]) as h2  (kk = k/2, 32 k-pairs)
__global__ void init_kernel(int* __restrict__ cursor,
                            const float* __restrict__ Wl, const float* __restrict__ Wr,
                            h2* __restrict__ wlh, h2* __restrict__ wrh, int n) {
    int i = blockIdx.x * 256 + threadIdx.x;
    if (i < n) cursor[i] = 0;
    if (i < 8192) {
        int kk = i >> 8, t = i & 255;
        wlh[i] = (h2){(_Float16)Wl[(2 * kk) * 256 + t], (_Float16)Wl[(2 * kk + 1) * 256 + t]};
        wrh[i] = (h2){(_Float16)Wr[(2 * kk) * 256 + t], (_Float16)Wr[(2 * kk + 1) * 256 + t]};
    }
}

// ---------------- K1: fill (blocks < EB) + transform (blocks >= EB), concurrent ----------------
__global__ __launch_bounds__(256) void prep_kernel(
    const int* __restrict__ ei, const float* __restrict__ ea,
    int* __restrict__ cursor, unsigned int* __restrict__ rec, float* __restrict__ partials,
    const float* __restrict__ x, const h2* __restrict__ wlh, const float* __restrict__ bl,
    const h2* __restrict__ wrh, const float* __restrict__ br,
    _Float16* __restrict__ xlh, _Float16* __restrict__ xrh,
    int N, int E, int EB) {
    int b = blockIdx.x, t = threadIdx.x;
    if (b < EB) {
        // ---- fill: bucket edges into per-dst slots (packed u32) + ea partial ----
        int i = b * 256 + t;
        float s = 0.f;
        if (i < E) {
            int src = ei[i];
            int dst = ei[E + i];
            float a = ea[i];
            s = a;
            int pos = atomicAdd(&cursor[dst], 1);
            if (pos < SLOT) {
                unsigned int pk = ((unsigned int)bits_f16((_Float16)a) << 16) | (unsigned int)src;
                rec[(size_t)dst * SLOT + pos] = pk;
            }
        }
        __shared__ float red[4];
#pragma unroll
        for (int o = 32; o >= 1; o >>= 1) s += __shfl_xor(s, o);
        if ((t & 63) == 0) red[t >> 6] = s;
        __syncthreads();
        if (t == 0) partials[b] = red[0] + red[1] + red[2] + red[3];
    } else {
        // ---- transform: 8 nodes/block, fp16-packed weights + FDOT2 (f32 accum) ----
        __shared__ h2 xs2[8][32];   // x rows as fp16 pairs; 2 KB
        int nb = (b - EB) * 8;
        int rows = N - nb; if (rows > 8) rows = 8;
        if (rows <= 0) return;
        if (t < rows * 16) {
            float4 xv = ((const float4*)(x + (size_t)nb * 64))[t];
            h4 hv = {(_Float16)xv.x, (_Float16)xv.y, (_Float16)xv.z, (_Float16)xv.w};
            *(h4*)&xs2[t >> 4][(t & 15) * 2] = hv;
        }
        __syncthreads();
        float blv = bl[t], brv = br[t];
        float accl[8], accr[8];
#pragma unroll
        for (int i = 0; i < 8; ++i) { accl[i] = blv; accr[i] = brv; }
        for (int kk = 0; kk < 32; kk += 2) {    // two k-pairs (= 4 k) per iter
            h2 wl0 = wlh[(kk + 0) * 256 + t], wl1 = wlh[(kk + 1) * 256 + t];
            h2 wr0 = wrh[(kk + 0) * 256 + t], wr1 = wrh[(kk + 1) * 256 + t];
#pragma unroll
            for (int i = 0; i < 8; ++i) {
                h4 xq = *(const h4*)&xs2[i][kk];   // broadcast, conflict-free
                h2 x0 = (h2){xq[0], xq[1]}, x1 = (h2){xq[2], xq[3]};
                accl[i] = FDOT2(x0, wl0, accl[i]);
                accl[i] = FDOT2(x1, wl1, accl[i]);
                accr[i] = FDOT2(x0, wr0, accr[i]);
                accr[i] = FDOT2(x1, wr1, accr[i]);
            }
        }
        for (int i = 0; i < rows; ++i) {
            xlh[(size_t)(nb + i) * 256 + t] = (_Float16)accl[i];
            xrh[(size_t)(nb + i) * 256 + t] = (_Float16)accr[i];
        }
    }
}

// ---------------- K2: reduce ea partials -> easum (premultiplied by 1/E) ----------------
__global__ __launch_bounds__(256) void easum_kernel(const float* __restrict__ partials,
                                                    float* __restrict__ easum, int eb, float inv_e) {
    float s = 0.f;
    for (int i = threadIdx.x; i < eb; i += 256) s += partials[i];
#pragma unroll
    for (int o = 32; o >= 1; o >>= 1) s += __shfl_xor(s, o);
    __shared__ float red[4];
    if ((threadIdx.x & 63) == 0) red[threadIdx.x >> 6] = s;
    __syncthreads();
    if (threadIdx.x == 0) easum[0] = (red[0] + red[1] + red[2] + red[3]) * inv_e;
}

// ---------------- K3: per-node GATv2, lane-resident records (readlane fetch) ----------------
__global__ __launch_bounds__(256) void gat_kernel(
    const _Float16* __restrict__ xlh, const _Float16* __restrict__ xrh,
    const int* __restrict__ cursor, const unsigned int* __restrict__ rec,
    const float* __restrict__ att, const float* __restrict__ We, const float* __restrict__ bias_conv,
    const float* __restrict__ easum, _Float16* __restrict__ hg, int n) {
    int wid = (blockIdx.x * blockDim.x + threadIdx.x) >> 6;
    if (wid >= n) return;
    int lane = threadIdx.x & 63;
    int half = lane >> 5, s = lane & 31;      // lane covers dims 8s..8s+7

    // one coalesced load: lane l holds record l of this node (garbage for l>=cnt, never used)
    int pkv = (int)rec[(size_t)wid * SLOT + lane];
    int cnt = cursor[wid]; if (cnt > SLOT) cnt = SLOT;   // wave-uniform

    h8 xrv = ((const h8*)xrh)[(size_t)wid * 32 + s];
    h2 xr2[4], we2[4], c02 = {(_Float16)NEG_SLOPE, (_Float16)NEG_SLOPE};
    float atf[8];
    const float* attp = att + 8 * s;
    const float* wep = We + 8 * s;
#pragma unroll
    for (int j = 0; j < 4; ++j) {
        xr2[j] = (h2){xrv[2 * j], xrv[2 * j + 1]};
        we2[j] = (h2){(_Float16)wep[2 * j], (_Float16)wep[2 * j + 1]};
        atf[2 * j] = attp[2 * j]; atf[2 * j + 1] = attp[2 * j + 1];
    }
    const h8* xl8 = (const h8*)xlh;

    auto edge_p = [&](h8 v, _Float16 ah) -> float {
        h2 a2 = {ah, ah};
        float p = 0.f;
#pragma unroll
        for (int j = 0; j < 4; ++j) {
            h2 vj = (h2){v[2 * j], v[2 * j + 1]};
            h2 m = a2 * we2[j] + (vj + xr2[j]);
            h2 l = __builtin_elementwise_max(m, m * c02);   // leaky relu
            p = fmaf((float)l[0], atf[2 * j], p);
            p = fmaf((float)l[1], atf[2 * j + 1], p);
        }
        return red8_dpp(p);
    };

    float M = -1e30f, S = 0.f;
    f8 accv = (f8)0.f;                        // ext_vector: guaranteed registers

#define ACC_FMA(V, W)                                        \
    _Pragma("unroll")                                        \
    for (int j = 0; j < 8; ++j) accv[j] = fmaf((float)(V)[j], (W), accv[j]);

#define ONLINE(P, V) {                                       \
        float newM = fmaxf(M, (P));                          \
        float sc = __expf(M - newM), w = __expf((P) - newM); \
        S = S * sc + w;                                      \
        accv *= sc;                                          \
        ACC_FMA(V, w);                                       \
        M = newM; }

// record (R)+2*(D)+half via EXEC-independent readlane pair + per-lane select
#define LOADE(D, R)                                                         \
    int lo##D = __builtin_amdgcn_readlane(pkv, (R) + 2 * (D));              \
    int hi##D = __builtin_amdgcn_readlane(pkv, (R) + 2 * (D) + 1);          \
    int pk##D = half ? hi##D : lo##D;                                       \
    h8 v##D = xl8[(size_t)(unsigned)(pk##D & 0xFFFF) * 32 + s];
#define PCOMP(D) float p##D = edge_p(v##D, f16_bits((unsigned short)((unsigned)pk##D >> 16)));

    // prologue: half 0 = self loop (always), half 1 = record 0 (if cnt>=1)
    {
        int pk0 = __builtin_amdgcn_readlane(pkv, 0);
        int src = wid;
        _Float16 ah = (_Float16)easum[0];
        if (half == 1 && cnt >= 1) {
            src = pk0 & 0xFFFF;
            ah = f16_bits((unsigned short)((unsigned)pk0 >> 16));
        }
        h8 v = xl8[(size_t)src * 32 + s];
        float p = edge_p(v, ah);
        if (half == 0 || cnt >= 1) {
            M = p; S = 1.f;
#pragma unroll
            for (int j = 0; j < 8; ++j) accv[j] = (float)v[j];
        }
    }
    // remaining records: 1..cnt-1, consumed in wave-uniform blocks
    int r = 1;
    for (; r + 15 < cnt; r += 16) {
        LOADE(0, r) LOADE(1, r) LOADE(2, r) LOADE(3, r)
        LOADE(4, r) LOADE(5, r) LOADE(6, r) LOADE(7, r)
        PCOMP(0) PCOMP(1) PCOMP(2) PCOMP(3)
        PCOMP(4) PCOMP(5) PCOMP(6) PCOMP(7)
        float pm = fmaxf(fmaxf(fmaxf(p0, p1), fmaxf(p2, p3)),
                         fmaxf(fmaxf(p4, p5), fmaxf(p6, p7)));
        if (__all(pm <= M + RESCALE_THR)) {   // defer-max fast path
            float w0 = __expf(p0 - M), w1 = __expf(p1 - M);
            float w2 = __expf(p2 - M), w3 = __expf(p3 - M);
            float w4 = __expf(p4 - M), w5 = __expf(p5 - M);
            float w6 = __expf(p6 - M), w7 = __expf(p7 - M);
            S += ((w0 + w1) + (w2 + w3)) + ((w4 + w5) + (w6 + w7));
            ACC_FMA(v0, w0); ACC_FMA(v1, w1); ACC_FMA(v2, w2); ACC_FMA(v3, w3);
            ACC_FMA(v4, w4); ACC_FMA(v5, w5); ACC_FMA(v6, w6); ACC_FMA(v7, w7);
        } else {
            ONLINE(p0, v0); ONLINE(p1, v1); ONLINE(p2, v2); ONLINE(p3, v3);
            ONLINE(p4, v4); ONLINE(p5, v5); ONLINE(p6, v6); ONLINE(p7, v7);
        }
    }
    for (; r + 7 < cnt; r += 8) {
        LOADE(0, r) LOADE(1, r) LOADE(2, r) LOADE(3, r)
        PCOMP(0) PCOMP(1) PCOMP(2) PCOMP(3)
        float pm = fmaxf(fmaxf(p0, p1), fmaxf(p2, p3));
        if (__all(pm <= M + RESCALE_THR)) {
            float w0 = __expf(p0 - M), w1 = __expf(p1 - M);
            float w2 = __expf(p2 - M), w3 = __expf(p3 - M);
            S += (w0 + w1) + (w2 + w3);
            ACC_FMA(v0, w0); ACC_FMA(v1, w1); ACC_FMA(v2, w2); ACC_FMA(v3, w3);
        } else {
            ONLINE(p0, v0); ONLINE(p1, v1); ONLINE(p2, v2); ONLINE(p3, v3);
        }
    }
    for (; r + 1 < cnt; r += 2) {
        int lo = __builtin_amdgcn_readlane(pkv, r);
        int hi = __builtin_amdgcn_readlane(pkv, r + 1);
        int pk0 = half ? hi : lo;
        h8 v0 = xl8[(size_t)(unsigned)(pk0 & 0xFFFF) * 32 + s];
        PCOMP(0)
        ONLINE(p0, v0);
    }
    if (r < cnt) {   // single leftover record: readlane is EXEC-independent
        int pk0 = __builtin_amdgcn_readlane(pkv, r);
        h8 v0 = xl8[(size_t)(unsigned)(pk0 & 0xFFFF) * 32 + s];
        float p0 = edge_p(v0, f16_bits((unsigned short)((unsigned)pk0 >> 16)));
        if (half == 0) ONLINE(p0, v0);
    }

    // merge the two half-wave softmax states
    float Mo = __shfl_xor(M, 32);
    float newM = fmaxf(M, Mo);
    float sc = __expf(M - newM);
    S *= sc;
    S += __shfl_xor(S, 32);
    accv *= sc;
#pragma unroll
    for (int j = 0; j < 8; ++j) accv[j] += __shfl_xor(accv[j], 32);
    float inv = 1.f / (S + 1e-16f);

    float4 bc = ((const float4*)bias_conv)[2 * s + half];
    int jb = 4 * half;
    h4 ov = {(_Float16)(accv[jb + 0] * inv + bc.x), (_Float16)(accv[jb + 1] * inv + bc.y),
             (_Float16)(accv[jb + 2] * inv + bc.z), (_Float16)(accv[jb + 3] * inv + bc.w)};
    ((h4*)hg)[(size_t)wid * 64 + 2 * s + half] = ov;
#undef ACC_FMA
#undef ONLINE
#undef LOADE
#undef PCOMP
}

// ---------------- K4: proj(256->64) + residual + ELU + LN (64 nodes, 512 thr) ----------------
__global__ __launch_bounds__(512) void proj_ln_kernel(
    const _Float16* __restrict__ hg, const float* __restrict__ Wp, const float* __restrict__ bp,
    const float* __restrict__ x, const float* __restrict__ gamma, const float* __restrict__ beta,
    float* __restrict__ out, int n) {
    __shared__ _Float16 wp_t[64 * 256];   // transposed [c][k], XOR-swizzled; 32 KB
    __shared__ _Float16 hs[64][264];      // [node][k], +8 pad; 33.8 KB
    int t = threadIdx.x;
    int nb = blockIdx.x * 64;
    for (int idx = t; idx < 4096; idx += 512) {
        float4 wv = ((const float4*)Wp)[idx];
        int k = idx >> 4, c0s = (idx & 15) * 4;
#pragma unroll
        for (int m = 0; m < 4; ++m) {
            int c = c0s + m;
            int off = c * 256 + ((((k >> 3) ^ ((c >> 2) & 7)) << 3) | (k & 7));
            wp_t[off] = (_Float16)((&wv.x)[m]);
        }
    }
    for (int idx = t; idx < 2048; idx += 512) {
        int row = idx >> 5, c8 = idx & 31;
        h8 hv = (h8)(_Float16)0.f;
        if (nb + row < n) hv = ((const h8*)hg)[(size_t)(nb + row) * 32 + c8];
        *(h8*)&hs[row][c8 * 8] = hv;
    }
    __syncthreads();

    int ng = t >> 4, cg = t & 15;     // 32 node-pairs x 16 col-groups
    int n0 = ng * 2, c0 = cg * 4;
    float acc[2][4];
#pragma unroll
    for (int a = 0; a < 2; ++a)
#pragma unroll
        for (int c = 0; c < 4; ++c) acc[a][c] = 0.f;

    for (int k = 0; k < 256; k += 8) {
        h8 hr[2], wr_[4];
#pragma unroll
        for (int a = 0; a < 2; ++a) hr[a] = *(const h8*)&hs[n0 + a][k];
#pragma unroll
        for (int j = 0; j < 4; ++j) {
            int c = c0 + j;
            int off = c * 256 + (((k >> 3) ^ ((c >> 2) & 7)) << 3);
            wr_[j] = *(const h8*)&wp_t[off];
        }
#pragma unroll
        for (int a = 0; a < 2; ++a) {
            const h2* hp = (const h2*)&hr[a];
#pragma unroll
            for (int j = 0; j < 4; ++j) {
                const h2* wp2 = (const h2*)&wr_[j];
                acc[a][j] = FDOT2(hp[0], wp2[0], acc[a][j]);
                acc[a][j] = FDOT2(hp[1], wp2[1], acc[a][j]);
                acc[a][j] = FDOT2(hp[2], wp2[2], acc[a][j]);
                acc[a][j] = FDOT2(hp[3], wp2[3], acc[a][j]);
            }
        }
    }

    float4 bpv = ((const float4*)bp)[cg];
    float4 gv  = ((const float4*)gamma)[cg];
    float4 bv  = ((const float4*)beta)[cg];
#pragma unroll
    for (int a = 0; a < 2; ++a) {
        int node = nb + n0 + a;
        float4 xv = make_float4(0.f, 0.f, 0.f, 0.f);
        if (node < n) xv = ((const float4*)x)[(size_t)node * 16 + cg];
        float h[4];
        h[0] = acc[a][0] + bpv.x + xv.x; h[1] = acc[a][1] + bpv.y + xv.y;
        h[2] = acc[a][2] + bpv.z + xv.z; h[3] = acc[a][3] + bpv.w + xv.w;
#pragma unroll
        for (int c = 0; c < 4; ++c) h[c] = h[c] > 0.f ? h[c] : expm1f(h[c]);
        float sum = h[0] + h[1] + h[2] + h[3];
#pragma unroll
        for (int o = 8; o >= 1; o >>= 1) sum += __shfl_xor(sum, o);
        float mu = sum * (1.f / 64.f);
        float d[4]; float s2 = 0.f;
#pragma unroll
        for (int c = 0; c < 4; ++c) { d[c] = h[c] - mu; s2 += d[c] * d[c]; }
#pragma unroll
        for (int o = 8; o >= 1; o >>= 1) s2 += __shfl_xor(s2, o);
        float r = rsqrtf(s2 * (1.f / 64.f) + LN_EPS);
        float4 ov;
        ov.x = d[0] * r * gv.x + bv.x; ov.y = d[1] * r * gv.y + bv.y;
        ov.z = d[2] * r * gv.z + bv.z; ov.w = d[3] * r * gv.w + bv.w;
        if (node < n) ((float4*)out)[(size_t)node * 16 + cg] = ov;
    }
}

// ---------------- launcher ----------------
extern "C" void kernel_launch(void* const* d_in, const int* in_sizes, int n_in,
                              void* d_out, int out_size, void* d_ws, size_t ws_size,
                              hipStream_t stream) {
    const float* x         = (const float*)d_in[0];
    const int*   ei        = (const int*)d_in[1];
    const float* ea        = (const float*)d_in[2];
    const float* Wl        = (const float*)d_in[3];
    const float* bl        = (const float*)d_in[4];
    const float* Wr        = (const float*)d_in[5];
    const float* br        = (const float*)d_in[6];
    const float* We        = (const float*)d_in[7];
    const float* att       = (const float*)d_in[8];
    const float* bias_conv = (const float*)d_in[9];
    const float* Wp        = (const float*)d_in[10];
    const float* bp        = (const float*)d_in[11];
    const float* gamma     = (const float*)d_in[12];
    const float* beta      = (const float*)d_in[13];
    float* out = (float*)d_out;

    int N = in_sizes[0] / 64;
    int E = in_sizes[2];
    int EB = (E + 255) / 256;          // fill blocks
    int TB = (N + 7) / 8;              // transform blocks

    char* w = (char*)d_ws;
    auto alloc = [&](size_t bytes) {
        char* p = w;
        w += (bytes + 255) & ~(size_t)255;
        return p;
    };
    _Float16*     xlh     = (_Float16*)    alloc((size_t)N * 256 * 2);
    _Float16*     xrh     = (_Float16*)    alloc((size_t)N * 256 * 2);
    _Float16*     hgh     = (_Float16*)    alloc((size_t)N * 256 * 2);
    unsigned int* rec     = (unsigned int*)alloc((size_t)N * SLOT * 4);
    int*          cursor  = (int*)         alloc((size_t)N * 4);
    float*        partials= (float*)       alloc((size_t)EB * 4);
    float*        easum   = (float*)       alloc(4);
    h2*           wlh     = (h2*)          alloc(8192 * 4);
    h2*           wrh     = (h2*)          alloc(8192 * 4);

    init_kernel<<<(N + 255) / 256, 256, 0, stream>>>(cursor, Wl, Wr, wlh, wrh, N);
    prep_kernel<<<EB + TB, 256, 0, stream>>>(ei, ea, cursor, rec, partials,
                                             x, wlh, bl, wrh, br, xlh, xrh, N, E, EB);
    easum_kernel<<<1, 256, 0, stream>>>(partials, easum, EB, 1.f / (float)E);
    gat_kernel<<<(N + 3) / 4, 256, 0, stream>>>(xlh, xrh, cursor, rec, att, We,
                                                bias_conv, easum, hgh, N);
    proj_ln_kernel<<<(N + 63) / 64, 512, 0, stream>>>(hgh, Wp, bp, x, gamma, beta, out, N);
}